// Round 8
// baseline (506.686 us; speedup 1.0000x reference)
//
#include <hip/hip_runtime.h>
#include <hip/hip_bf16.h>

#define HDIM 128
#define TB_LD 1152   // Tball leading dim = 3 relations x 384
#define BCAP 8192    // per-bucket capacity (avg fill ~3060, uniform dst)
#define NBUCK 256    // max buckets (N<=65536, 256 nodes/bucket)

typedef __attribute__((ext_vector_type(8))) short short8;
typedef __attribute__((ext_vector_type(16))) float floatx16;

#define GF_LEAKY 1
#define GF_BF16  4

// ---------------------------------------------------------------------------
// LDS-staged bf16 MFMA GEMM, batched over blockIdx.y with element offsets.
// Block: BM=128 x BN=128, BK=64. 256 thr = 4 waves 2x2, wave tile 64x64.
// ---------------------------------------------------------------------------
__global__ __launch_bounds__(256) void gemm_lds_kernel(
    const __hip_bfloat16* __restrict__ A, int lda, int aOff,
    const __hip_bfloat16* __restrict__ Bt, int ldb, int bRowOff,
    const float* __restrict__ bias, int biasOff,
    void* __restrict__ Cout, int ldc, int cColOff,
    int M, int K, int flags)
{
    __shared__ short As[128 * 64];
    __shared__ short Bs[128 * 64];

    const int tid  = threadIdx.x;
    const int lane = tid & 63;
    const int wave = tid >> 6;
    const int wm   = (wave >> 1) << 6;
    const int wn   = (wave & 1) << 6;
    const int l31  = lane & 31;
    const int ch   = lane >> 5;
    const int e7   = l31 & 7;

    const int m0 = blockIdx.x * 128;
    const int y  = blockIdx.y;

    const short* Ab = (const short*)A + (size_t)y * aOff;
    const short* Bb = (const short*)Bt + (size_t)y * bRowOff * ldb;

    const int rr = tid >> 3;
    const int cc = tid & 7;
    const int sbase = rr * 64 + (((cc ^ (rr & 7)) << 3));
    const short* pA[4];
    const short* pB[4];
#pragma unroll
    for (int i = 0; i < 4; i++) {
        int r = i * 32 + rr;
        int gr = m0 + r; gr = gr < M ? gr : (M - 1);
        pA[i] = Ab + (size_t)gr * lda + cc * 8;
        pB[i] = Bb + (size_t)r * ldb + cc * 8;
    }

    floatx16 acc[2][2];
#pragma unroll
    for (int a = 0; a < 2; a++)
#pragma unroll
        for (int b = 0; b < 2; b++)
#pragma unroll
            for (int i = 0; i < 16; i++) acc[a][b][i] = 0.f;

    const int ra0 = (wm + l31) * 64;
    const int ra1 = (wm + 32 + l31) * 64;
    const int rb0 = (wn + l31) * 64;
    const int rb1 = (wn + 32 + l31) * 64;

    for (int k0 = 0; k0 < K; k0 += 64) {
#pragma unroll
        for (int i = 0; i < 4; i++) {
            int4 av = *(const int4*)(pA[i] + k0);
            int4 bv = *(const int4*)(pB[i] + k0);
            *(int4*)(As + i * 2048 + sbase) = av;
            *(int4*)(Bs + i * 2048 + sbase) = bv;
        }
        __syncthreads();
#pragma unroll
        for (int ks = 0; ks < 4; ks++) {
            const int sw = (((ks << 1) + ch) ^ e7) << 3;
            short8 a0 = *(const short8*)(As + ra0 + sw);
            short8 a1 = *(const short8*)(As + ra1 + sw);
            short8 b0 = *(const short8*)(Bs + rb0 + sw);
            short8 b1 = *(const short8*)(Bs + rb1 + sw);
            acc[0][0] = __builtin_amdgcn_mfma_f32_32x32x16_bf16(a0, b0, acc[0][0], 0, 0, 0);
            acc[0][1] = __builtin_amdgcn_mfma_f32_32x32x16_bf16(a0, b1, acc[0][1], 0, 0, 0);
            acc[1][0] = __builtin_amdgcn_mfma_f32_32x32x16_bf16(a1, b0, acc[1][0], 0, 0, 0);
            acc[1][1] = __builtin_amdgcn_mfma_f32_32x32x16_bf16(a1, b1, acc[1][1], 0, 0, 0);
        }
        __syncthreads();
    }

    const int colL0 = wn + l31;
    const int ccol  = y * cColOff;
    const float bv0 = bias ? bias[y * biasOff + colL0] : 0.f;
    const float bv1 = bias ? bias[y * biasOff + colL0 + 32] : 0.f;
    const int rb = m0 + wm + ((lane >> 5) << 2);

#pragma unroll
    for (int tm = 0; tm < 2; tm++) {
#pragma unroll
        for (int rg = 0; rg < 16; rg++) {
            int row = rb + tm * 32 + (rg & 3) + ((rg >> 2) << 3);
            if (row >= M) continue;
            float v0 = acc[tm][0][rg] + bv0;
            float v1 = acc[tm][1][rg] + bv1;
            if (flags & GF_LEAKY) {
                v0 = v0 > 0.f ? v0 : 0.01f * v0;
                v1 = v1 > 0.f ? v1 : 0.01f * v1;
            }
            if (flags & GF_BF16) {
                __hip_bfloat16* C = (__hip_bfloat16*)Cout;
                C[(size_t)row * ldc + ccol + colL0]      = __float2bfloat16(v0);
                C[(size_t)row * ldc + ccol + colL0 + 32] = __float2bfloat16(v1);
            } else {
                float* C = (float*)Cout;
                C[(size_t)row * ldc + ccol + colL0]      = v0;
                C[(size_t)row * ldc + ccol + colL0 + 32] = v1;
            }
        }
    }
}

// ---------------------------------------------------------------------------
// Same GEMM but A is fp32 (converted to bf16 during LDS staging). Used for G1
// (A = x), removing the separate cvt_x kernel and the xb round-trip.
// ---------------------------------------------------------------------------
__global__ __launch_bounds__(256) void gemm_lds_a32_kernel(
    const float* __restrict__ A, int lda,
    const __hip_bfloat16* __restrict__ Bt, int ldb, int bRowOff,
    const float* __restrict__ bias, int biasOff,
    __hip_bfloat16* __restrict__ Cout, int ldc, int cColOff,
    int M, int K)
{
    __shared__ short As[128 * 64];
    __shared__ short Bs[128 * 64];

    const int tid  = threadIdx.x;
    const int lane = tid & 63;
    const int wave = tid >> 6;
    const int wm   = (wave >> 1) << 6;
    const int wn   = (wave & 1) << 6;
    const int l31  = lane & 31;
    const int ch   = lane >> 5;
    const int e7   = l31 & 7;

    const int m0 = blockIdx.x * 128;
    const int y  = blockIdx.y;
    const short* Bb = (const short*)Bt + (size_t)y * bRowOff * ldb;

    const int rr = tid >> 3;
    const int cc = tid & 7;
    const int sbase = rr * 64 + (((cc ^ (rr & 7)) << 3));
    const float* pA[4];
    const short* pB[4];
#pragma unroll
    for (int i = 0; i < 4; i++) {
        int r = i * 32 + rr;
        int gr = m0 + r; gr = gr < M ? gr : (M - 1);
        pA[i] = A + (size_t)gr * lda + cc * 8;
        pB[i] = Bb + (size_t)r * ldb + cc * 8;
    }

    floatx16 acc[2][2];
#pragma unroll
    for (int a = 0; a < 2; a++)
#pragma unroll
        for (int b = 0; b < 2; b++)
#pragma unroll
            for (int i = 0; i < 16; i++) acc[a][b][i] = 0.f;

    const int ra0 = (wm + l31) * 64;
    const int ra1 = (wm + 32 + l31) * 64;
    const int rb0 = (wn + l31) * 64;
    const int rb1 = (wn + 32 + l31) * 64;

    for (int k0 = 0; k0 < K; k0 += 64) {
#pragma unroll
        for (int i = 0; i < 4; i++) {
            float4 a0 = *(const float4*)(pA[i] + k0);
            float4 a1 = *(const float4*)(pA[i] + k0 + 4);
            int4 bv = *(const int4*)(pB[i] + k0);
            __hip_bfloat16 o[8] = {
                __float2bfloat16(a0.x), __float2bfloat16(a0.y),
                __float2bfloat16(a0.z), __float2bfloat16(a0.w),
                __float2bfloat16(a1.x), __float2bfloat16(a1.y),
                __float2bfloat16(a1.z), __float2bfloat16(a1.w)};
            *(int4*)(As + i * 2048 + sbase) = *(int4*)o;
            *(int4*)(Bs + i * 2048 + sbase) = bv;
        }
        __syncthreads();
#pragma unroll
        for (int ks = 0; ks < 4; ks++) {
            const int sw = (((ks << 1) + ch) ^ e7) << 3;
            short8 a0 = *(const short8*)(As + ra0 + sw);
            short8 a1 = *(const short8*)(As + ra1 + sw);
            short8 b0 = *(const short8*)(Bs + rb0 + sw);
            short8 b1 = *(const short8*)(Bs + rb1 + sw);
            acc[0][0] = __builtin_amdgcn_mfma_f32_32x32x16_bf16(a0, b0, acc[0][0], 0, 0, 0);
            acc[0][1] = __builtin_amdgcn_mfma_f32_32x32x16_bf16(a0, b1, acc[0][1], 0, 0, 0);
            acc[1][0] = __builtin_amdgcn_mfma_f32_32x32x16_bf16(a1, b0, acc[1][0], 0, 0, 0);
            acc[1][1] = __builtin_amdgcn_mfma_f32_32x32x16_bf16(a1, b1, acc[1][1], 0, 0, 0);
        }
        __syncthreads();
    }

    const int colL0 = wn + l31;
    const int ccol  = y * cColOff;
    const float bv0 = bias ? bias[y * biasOff + colL0] : 0.f;
    const float bv1 = bias ? bias[y * biasOff + colL0 + 32] : 0.f;
    const int rb = m0 + wm + ((lane >> 5) << 2);

#pragma unroll
    for (int tm = 0; tm < 2; tm++) {
#pragma unroll
        for (int rg = 0; rg < 16; rg++) {
            int row = rb + tm * 32 + (rg & 3) + ((rg >> 2) << 3);
            if (row >= M) continue;
            float v0 = acc[tm][0][rg] + bv0;
            float v1 = acc[tm][1][rg] + bv1;
            v0 = v0 > 0.f ? v0 : 0.01f * v0;
            v1 = v1 > 0.f ? v1 : 0.01f * v1;
            Cout[(size_t)row * ldc + ccol + colL0]      = __float2bfloat16(v0);
            Cout[(size_t)row * ldc + ccol + colL0 + 32] = __float2bfloat16(v1);
        }
    }
}

// ---------------------------------------------------------------------------
// All weight prep in ONE kernel (W1t, W2t, W3et replicated, b1c, b2c).
// ---------------------------------------------------------------------------
__global__ __launch_bounds__(256) void prep_weights_kernel(
    const float* __restrict__ W1_0, const float* __restrict__ W1_1, const float* __restrict__ W1_2,
    const float* __restrict__ W2_0, const float* __restrict__ W2_1, const float* __restrict__ W2_2,
    const float* __restrict__ W3,
    const float* __restrict__ b1_0, const float* __restrict__ b1_1, const float* __restrict__ b1_2,
    const float* __restrict__ b2_0, const float* __restrict__ b2_1, const float* __restrict__ b2_2,
    __hip_bfloat16* __restrict__ W1t, __hip_bfloat16* __restrict__ W2t,
    __hip_bfloat16* __restrict__ W3et, float* __restrict__ b1c, float* __restrict__ b2c)
{
    int idx = blockIdx.x * 256 + threadIdx.x;
    if (idx < 98304) {                       // W1: 3 * 256*128
        int r = idx >> 15, rem = idx & 32767;
        int k = rem >> 7, n = rem & 127;
        const float* W = (r == 0) ? W1_0 : (r == 1) ? W1_1 : W1_2;
        W1t[(size_t)(r * 128 + n) * 256 + k] = __float2bfloat16(W[rem]);
    } else if (idx < 147456) {               // W2: 3 * 128*128
        int j = idx - 98304;
        int r = j >> 14, rem = j & 16383;
        int k = rem >> 7, n = rem & 127;
        const float* W = (r == 0) ? W2_0 : (r == 1) ? W2_1 : W2_2;
        W2t[(size_t)r * 16384 + n * 128 + k] = __float2bfloat16(W[rem]);
    } else if (idx < 196608) {               // W3eff: 384*128, replicated x3
        int j = idx - 147456;
        int row = j >> 7, c = j & 127;
        int kk = row >> 7, hh = row & 127;
        const float t[3][3] = {{3.f, -3.f, 0.75f},
                               {0.f,  3.f, -1.5f},
                               {0.f,  0.f, 0.75f}};
        float s = 0.f;
        for (int jj = 0; jj < 3; jj++)
            s += t[jj][kk] * W3[((size_t)jj * HDIM + hh) * HDIM + c];
        __hip_bfloat16 sb = __float2bfloat16(s);
        W3et[(size_t)c * TB_LD + row]       = sb;
        W3et[(size_t)c * TB_LD + 384 + row] = sb;
        W3et[(size_t)c * TB_LD + 768 + row] = sb;
    } else if (idx < 196992) {               // b1c
        int j = idx - 196608;
        const float* b = (j < 128) ? b1_0 : (j < 256) ? b1_1 : b1_2;
        b1c[j] = b[j & 127];
    } else if (idx < 197376) {               // b2c
        int j = idx - 196992;
        const float* b = (j < 128) ? b2_0 : (j < 256) ? b2_1 : b2_2;
        b2c[j] = b[j & 127];
    }
}

// ---------------------------------------------------------------------------
// Bucketed CSR build. Bucket = 256 consecutive dst nodes. Edges packed as
// src | (dst&255)<<16  (N <= 65536). Block-private claimed runs -> writes
// merge in one XCD's L2 (avoids cross-XCD 4B scatter HBM RMW).
// ---------------------------------------------------------------------------
__global__ __launch_bounds__(256) void bin_kernel(
    const int* __restrict__ s0, const int* __restrict__ s1, const int* __restrict__ s2,
    const int* __restrict__ d0, const int* __restrict__ d1, const int* __restrict__ d2,
    int* __restrict__ bcur,      // [3][NBUCK], pre-zeroed
    int* __restrict__ binned,    // [3][NBUCK][BCAP]
    int nE)
{
    __shared__ int hist[NBUCK];
    __shared__ int claim[NBUCK];
    const int t = threadIdx.x;
    const int y = blockIdx.y;
    const int* sp = (y == 0) ? s0 : (y == 1) ? s1 : s2;
    const int* dp = (y == 0) ? d0 : (y == 1) ? d1 : d2;
    const int base = blockIdx.x * 4096;

    hist[t] = 0;
    __syncthreads();

    int pk[16], bk[16], rk[16];
#pragma unroll
    for (int j = 0; j < 16; j++) {
        int e = base + j * 256 + t;
        if (e < nE) {
            int s = sp[e], d = dp[e];
            bk[j] = d >> 8;
            pk[j] = s | ((d & 255) << 16);
            rk[j] = atomicAdd(&hist[bk[j]], 1);
        } else {
            bk[j] = -1;
        }
    }
    __syncthreads();
    int cnt = hist[t];
    claim[t] = (cnt > 0) ? atomicAdd(&bcur[y * NBUCK + t], cnt) : 0;
    __syncthreads();
#pragma unroll
    for (int j = 0; j < 16; j++) {
        if (bk[j] >= 0) {
            int pos = claim[bk[j]] + rk[j];
            if (pos < BCAP)
                binned[((size_t)(y * NBUCK + bk[j])) * BCAP + pos] = pk[j];
        }
    }
}

// Exclusive scan of per-bucket counts -> bucket edge-base offsets (1 block).
__global__ __launch_bounds__(256) void scan_bcur_kernel(
    const int* __restrict__ bcur, int* __restrict__ bbase)
{
    __shared__ int sdata[256];
    const int t = threadIdx.x;
    for (int y = 0; y < 3; y++) {
        int v = bcur[y * NBUCK + t];
        sdata[t] = v;
        __syncthreads();
        for (int off = 1; off < 256; off <<= 1) {
            int x = (t >= off) ? sdata[t - off] : 0;
            __syncthreads();
            sdata[t] += x;
            __syncthreads();
        }
        bbase[y * NBUCK + t] = sdata[t] - v;
        __syncthreads();
    }
}

// One block per bucket: LDS histogram + LDS scan -> rowstart AND dinv
// directly (replaces 3 N-wide scan kernels).
__global__ __launch_bounds__(256) void deg_kernel2(
    const int* __restrict__ bcur, const int* __restrict__ bbase,
    const int* __restrict__ binned,
    int* __restrict__ rowstart, float* __restrict__ dinvAll, int N)
{
    __shared__ int hist[256];
    __shared__ int scanbuf[256];
    const int t = threadIdx.x;
    const int b = blockIdx.x;
    const int y = blockIdx.y;
    hist[t] = 0;
    __syncthreads();
    const int count = bcur[y * NBUCK + b];
    const int* eb = binned + ((size_t)(y * NBUCK + b)) * BCAP;
    for (int i = t; i < count; i += 256)
        atomicAdd(&hist[(eb[i] >> 16) & 255], 1);
    __syncthreads();
    int hv = hist[t];
    scanbuf[t] = hv;
    __syncthreads();
    for (int off = 1; off < 256; off <<= 1) {
        int x = (t >= off) ? scanbuf[t - off] : 0;
        __syncthreads();
        scanbuf[t] += x;
        __syncthreads();
    }
    int excl = scanbuf[t] - hv;
    int node = (b << 8) + t;
    int base = bbase[y * NBUCK + b];
    if (node < N) {
        rowstart[(size_t)y * (N + 1) + node] = base + excl;
        float d = hv > 1 ? (float)hv : 1.0f;
        dinvAll[(size_t)y * N + node] = 1.0f / sqrtf(d);
    } else if (node == N) {
        rowstart[(size_t)y * (N + 1) + node] = base + excl;   // == E
    }
}

// One block per bucket: LDS cursors from rowstart, scatter ushort src indices
// into the bucket's confined ebuf region.
__global__ __launch_bounds__(256) void place_kernel2(
    const int* __restrict__ bcur, const int* __restrict__ binned,
    const int* __restrict__ rowstart, unsigned short* __restrict__ ebuf,
    int N, int nE)
{
    __shared__ int cur[256];
    const int t = threadIdx.x;
    const int b = blockIdx.x;
    const int y = blockIdx.y;
    int node = (b << 8) + t;
    cur[t] = rowstart[(size_t)y * (N + 1) + (node < N ? node : N)];
    __syncthreads();
    const int count = bcur[y * NBUCK + b];
    const int* eb = binned + ((size_t)(y * NBUCK + b)) * BCAP;
    unsigned short* ebo = ebuf + (size_t)y * nE;
    for (int i = t; i < count; i += 256) {
        int p = eb[i];
        int pos = atomicAdd(&cur[(p >> 16) & 255], 1);
        ebo[pos] = (unsigned short)(p & 0xFFFF);
    }
}

// ---------------------------------------------------------------------------
// Column-split gather-aggregate + fixup (fp32 accumulation).
// gridDim.y = 12 pairs: pair = (rel = y>>2, colblock = y&3), 32 cols each.
// Per node: 4 lanes x 16 B = one 64 B cache line per source -> working set
// per pair = N*64 B = 3.2 MB (< 4 MB XCD L2), vs 38.4 MB unsplit (R7: 57%
// L2 hit, 198 MB HBM fetch). Per-column sum order identical to R7.
// ---------------------------------------------------------------------------
__device__ inline float bflo(unsigned u) {
    return __builtin_bit_cast(float, u << 16);
}
__device__ inline float bfhi(unsigned u) {
    return __builtin_bit_cast(float, u & 0xffff0000u);
}

__device__ inline void acc8(float* s, uint4 u, float w) {
    s[0] += bflo(u.x) * w; s[1] += bfhi(u.x) * w;
    s[2] += bflo(u.y) * w; s[3] += bfhi(u.y) * w;
    s[4] += bflo(u.z) * w; s[5] += bfhi(u.z) * w;
    s[6] += bflo(u.w) * w; s[7] += bfhi(u.w) * w;
}

__global__ __launch_bounds__(256) void gather_agg_kernel(
    const int* __restrict__ rowstart, const unsigned short* __restrict__ ebufAll,
    const float* __restrict__ dinvAll, __hip_bfloat16* __restrict__ T,
    int inBase, int outBase, int N, int nE)
{
    const int v = blockIdx.x * 64 + (threadIdx.x >> 2);
    if (v >= N) return;
    const int y   = blockIdx.y;
    const int rel = y >> 2;
    const int cb  = y & 3;
    const int* rs = rowstart + (size_t)rel * (N + 1);
    const unsigned short* eb = ebufAll + (size_t)rel * nE;
    const float* dinv = dinvAll + (size_t)rel * N;
    const int inOff  = rel * 384 + inBase  + cb * 32 + (threadIdx.x & 3) * 8;
    const int outOff = rel * 384 + outBase + cb * 32 + (threadIdx.x & 3) * 8;

    const unsigned short* Tu = (const unsigned short*)T;
    const int beg = rs[v];
    const int end = rs[v + 1];

    float s[8];
#pragma unroll
    for (int j = 0; j < 8; j++) s[j] = 0.f;

    int i = beg;
    for (; i + 3 < end; i += 4) {
        int a = eb[i], b = eb[i + 1], c = eb[i + 2], d = eb[i + 3];
        float wa = dinv[a], wb = dinv[b], wc = dinv[c], wd = dinv[d];
        uint4 ua = *(const uint4*)(Tu + (size_t)a * TB_LD + inOff);
        uint4 ub = *(const uint4*)(Tu + (size_t)b * TB_LD + inOff);
        uint4 uc = *(const uint4*)(Tu + (size_t)c * TB_LD + inOff);
        uint4 ud = *(const uint4*)(Tu + (size_t)d * TB_LD + inOff);
        acc8(s, ua, wa); acc8(s, ub, wb); acc8(s, uc, wc); acc8(s, ud, wd);
    }
    for (; i < end; i++) {
        int a = eb[i];
        float wa = dinv[a];
        uint4 ua = *(const uint4*)(Tu + (size_t)a * TB_LD + inOff);
        acc8(s, ua, wa);
    }

    const float di = dinv[v];
    uint4 uv = *(const uint4*)(Tu + (size_t)v * TB_LD + inOff);
    float r[8] = {bflo(uv.x) - s[0] * di, bfhi(uv.x) - s[1] * di,
                  bflo(uv.y) - s[2] * di, bfhi(uv.y) - s[3] * di,
                  bflo(uv.z) - s[4] * di, bfhi(uv.z) - s[5] * di,
                  bflo(uv.w) - s[6] * di, bfhi(uv.w) - s[7] * di};
    __hip_bfloat16 o[8];
#pragma unroll
    for (int j = 0; j < 8; j++) o[j] = __float2bfloat16(r[j]);
    *(uint4*)(T + (size_t)v * TB_LD + outOff) = *(uint4*)o;
}

// ---------------------------------------------------------------------------
extern "C" void kernel_launch(void* const* d_in, const int* in_sizes, int n_in,
                              void* d_out, int out_size, void* d_ws, size_t ws_size,
                              hipStream_t stream)
{
    const int N = in_sizes[0] / 256;
    const int E = in_sizes[1];
    const int IN = 256;

    const float* x = (const float*)d_in[0];
    const int* srcp[3]; const int* dstp[3];
    const float *W1p[3], *b1p[3], *W2p[3], *b2p[3];
    if (in_sizes[3] == E) {
        for (int r = 0; r < 3; r++) {
            srcp[r] = (const int*)d_in[1 + 2 * r];
            dstp[r] = (const int*)d_in[2 + 2 * r];
            W1p[r]  = (const float*)d_in[7 + 4 * r];
            b1p[r]  = (const float*)d_in[8 + 4 * r];
            W2p[r]  = (const float*)d_in[9 + 4 * r];
            b2p[r]  = (const float*)d_in[10 + 4 * r];
        }
    } else {
        for (int r = 0; r < 3; r++) {
            int base = 1 + 6 * r;
            srcp[r] = (const int*)d_in[base];
            dstp[r] = (const int*)d_in[base + 1];
            W1p[r]  = (const float*)d_in[base + 2];
            b1p[r]  = (const float*)d_in[base + 3];
            W2p[r]  = (const float*)d_in[base + 4];
            b2p[r]  = (const float*)d_in[base + 5];
        }
    }
    const float* W3 = (const float*)d_in[19];
    const float* b3 = (const float*)d_in[20];
    float* out = (float*)d_out;

    // Workspace (256B-aligned chunks)
    char* w = (char*)d_ws;
    auto alloc = [&](size_t bytes) { char* p = w; w += (bytes + 255) & ~(size_t)255; return p; };
    __hip_bfloat16* Tball = (__hip_bfloat16*)alloc((size_t)N * TB_LD * 2);
    __hip_bfloat16* Hb    = (__hip_bfloat16*)alloc((size_t)N * 384 * 2);
    __hip_bfloat16* W1t   = (__hip_bfloat16*)alloc((size_t)384 * IN * 2);
    __hip_bfloat16* W2t   = (__hip_bfloat16*)alloc((size_t)3 * HDIM * HDIM * 2);
    __hip_bfloat16* W3et  = (__hip_bfloat16*)alloc((size_t)HDIM * TB_LD * 2);
    float* b1c    = (float*)alloc(384 * 4);
    float* b2c    = (float*)alloc(384 * 4);
    float* dinv   = (float*)alloc((size_t)3 * N * 4);
    int* rowstart = (int*)alloc((size_t)3 * (N + 1) * 4);
    int* bcur     = (int*)alloc((size_t)3 * NBUCK * 4);
    int* bbase    = (int*)alloc((size_t)3 * NBUCK * 4);
    unsigned short* ebuf = (unsigned short*)alloc((size_t)3 * E * 2);
    int* binned   = (int*)alloc((size_t)3 * NBUCK * BCAP * 4);

    const int mGrid = (N + 127) / 128;
    const int nBuck = (N + 255) >> 8;
    const int binGrid = (E + 4095) / 4096;
    const int gGrid = (N + 63) / 64;

    // ---- prep ----
    prep_weights_kernel<<<(197376 + 255) / 256, 256, 0, stream>>>(
        W1p[0], W1p[1], W1p[2], W2p[0], W2p[1], W2p[2], W3,
        b1p[0], b1p[1], b1p[2], b2p[0], b2p[1], b2p[2],
        W1t, W2t, W3et, b1c, b2c);

    // ---- bucketed CSR build (all relations) ----
    hipMemsetAsync(bcur, 0, (size_t)3 * NBUCK * sizeof(int), stream);
    bin_kernel<<<dim3(binGrid, 3), 256, 0, stream>>>(
        srcp[0], srcp[1], srcp[2], dstp[0], dstp[1], dstp[2], bcur, binned, E);
    scan_bcur_kernel<<<1, 256, 0, stream>>>(bcur, bbase);
    deg_kernel2<<<dim3(nBuck, 3), 256, 0, stream>>>(bcur, bbase, binned,
                                                    rowstart, dinv, N);
    place_kernel2<<<dim3(nBuck, 3), 256, 0, stream>>>(bcur, binned, rowstart,
                                                      ebuf, N, E);

    // ---- G1: Hb[N,384] = leaky(x(fp32) @ [W1_0|W1_1|W1_2] + b1c) ----
    gemm_lds_a32_kernel<<<dim3(mGrid, 3), 256, 0, stream>>>(
        x, IN, W1t, IN, 128, b1c, 128, Hb, 384, 128, N, IN);

    // ---- G2: Tball[:, y*384:+128] = leaky(Hb[:, y*128:+128] @ W2_y + b2_y)
    gemm_lds_kernel<<<dim3(mGrid, 3), 256, 0, stream>>>(
        Hb, 384, 128, W2t, HDIM, 128, b2c, 128, Tball, TB_LD, 384, N, HDIM,
        GF_LEAKY | GF_BF16);

    // ---- poly features: hop1 (h -> f1), hop2 (f1 -> f2), 12 pairs each ----
    gather_agg_kernel<<<dim3(gGrid, 12), 256, 0, stream>>>(
        rowstart, ebuf, dinv, Tball, 0, 128, N, E);
    gather_agg_kernel<<<dim3(gGrid, 12), 256, 0, stream>>>(
        rowstart, ebuf, dinv, Tball, 128, 256, N, E);

    // ---- final: out = leaky(Tball @ W3et_cat + b3), K=1152, one shot ----
    gemm_lds_kernel<<<dim3(mGrid, 1), 256, 0, stream>>>(
        Tball, TB_LD, 0, W3et, TB_LD, 0, b3, 0, out, HDIM, 0, N, TB_LD,
        GF_LEAKY);
}

// Round 9
// 405.965 us; speedup vs baseline: 1.2481x; 1.2481x over previous
//
#include <hip/hip_runtime.h>
#include <hip/hip_bf16.h>

#define HDIM 128
#define TB_LD 1152   // Tball leading dim = 3 relations x 384
#define BCAP 8192    // per-bucket capacity (avg fill ~3060, uniform dst)
#define NBUCK 256    // max buckets (N<=65536, 256 nodes/bucket)

typedef __attribute__((ext_vector_type(8))) short short8;
typedef __attribute__((ext_vector_type(16))) float floatx16;

#define GF_LEAKY 1
#define GF_BF16  4

// ---------------------------------------------------------------------------
// LDS-staged bf16 MFMA GEMM, batched over blockIdx.y with element offsets.
// Block: BM=128 x BN=128, BK=64. 256 thr = 4 waves 2x2, wave tile 64x64.
// ---------------------------------------------------------------------------
__global__ __launch_bounds__(256) void gemm_lds_kernel(
    const __hip_bfloat16* __restrict__ A, int lda, int aOff,
    const __hip_bfloat16* __restrict__ Bt, int ldb, int bRowOff,
    const float* __restrict__ bias, int biasOff,
    void* __restrict__ Cout, int ldc, int cColOff,
    int M, int K, int flags)
{
    __shared__ short As[128 * 64];
    __shared__ short Bs[128 * 64];

    const int tid  = threadIdx.x;
    const int lane = tid & 63;
    const int wave = tid >> 6;
    const int wm   = (wave >> 1) << 6;
    const int wn   = (wave & 1) << 6;
    const int l31  = lane & 31;
    const int ch   = lane >> 5;
    const int e7   = l31 & 7;

    const int m0 = blockIdx.x * 128;
    const int y  = blockIdx.y;

    const short* Ab = (const short*)A + (size_t)y * aOff;
    const short* Bb = (const short*)Bt + (size_t)y * bRowOff * ldb;

    const int rr = tid >> 3;
    const int cc = tid & 7;
    const int sbase = rr * 64 + (((cc ^ (rr & 7)) << 3));
    const short* pA[4];
    const short* pB[4];
#pragma unroll
    for (int i = 0; i < 4; i++) {
        int r = i * 32 + rr;
        int gr = m0 + r; gr = gr < M ? gr : (M - 1);
        pA[i] = Ab + (size_t)gr * lda + cc * 8;
        pB[i] = Bb + (size_t)r * ldb + cc * 8;
    }

    floatx16 acc[2][2];
#pragma unroll
    for (int a = 0; a < 2; a++)
#pragma unroll
        for (int b = 0; b < 2; b++)
#pragma unroll
            for (int i = 0; i < 16; i++) acc[a][b][i] = 0.f;

    const int ra0 = (wm + l31) * 64;
    const int ra1 = (wm + 32 + l31) * 64;
    const int rb0 = (wn + l31) * 64;
    const int rb1 = (wn + 32 + l31) * 64;

    for (int k0 = 0; k0 < K; k0 += 64) {
#pragma unroll
        for (int i = 0; i < 4; i++) {
            int4 av = *(const int4*)(pA[i] + k0);
            int4 bv = *(const int4*)(pB[i] + k0);
            *(int4*)(As + i * 2048 + sbase) = av;
            *(int4*)(Bs + i * 2048 + sbase) = bv;
        }
        __syncthreads();
#pragma unroll
        for (int ks = 0; ks < 4; ks++) {
            const int sw = (((ks << 1) + ch) ^ e7) << 3;
            short8 a0 = *(const short8*)(As + ra0 + sw);
            short8 a1 = *(const short8*)(As + ra1 + sw);
            short8 b0 = *(const short8*)(Bs + rb0 + sw);
            short8 b1 = *(const short8*)(Bs + rb1 + sw);
            acc[0][0] = __builtin_amdgcn_mfma_f32_32x32x16_bf16(a0, b0, acc[0][0], 0, 0, 0);
            acc[0][1] = __builtin_amdgcn_mfma_f32_32x32x16_bf16(a0, b1, acc[0][1], 0, 0, 0);
            acc[1][0] = __builtin_amdgcn_mfma_f32_32x32x16_bf16(a1, b0, acc[1][0], 0, 0, 0);
            acc[1][1] = __builtin_amdgcn_mfma_f32_32x32x16_bf16(a1, b1, acc[1][1], 0, 0, 0);
        }
        __syncthreads();
    }

    const int colL0 = wn + l31;
    const int ccol  = y * cColOff;
    const float bv0 = bias ? bias[y * biasOff + colL0] : 0.f;
    const float bv1 = bias ? bias[y * biasOff + colL0 + 32] : 0.f;
    const int rb = m0 + wm + ((lane >> 5) << 2);

#pragma unroll
    for (int tm = 0; tm < 2; tm++) {
#pragma unroll
        for (int rg = 0; rg < 16; rg++) {
            int row = rb + tm * 32 + (rg & 3) + ((rg >> 2) << 3);
            if (row >= M) continue;
            float v0 = acc[tm][0][rg] + bv0;
            float v1 = acc[tm][1][rg] + bv1;
            if (flags & GF_LEAKY) {
                v0 = v0 > 0.f ? v0 : 0.01f * v0;
                v1 = v1 > 0.f ? v1 : 0.01f * v1;
            }
            if (flags & GF_BF16) {
                __hip_bfloat16* C = (__hip_bfloat16*)Cout;
                C[(size_t)row * ldc + ccol + colL0]      = __float2bfloat16(v0);
                C[(size_t)row * ldc + ccol + colL0 + 32] = __float2bfloat16(v1);
            } else {
                float* C = (float*)Cout;
                C[(size_t)row * ldc + ccol + colL0]      = v0;
                C[(size_t)row * ldc + ccol + colL0 + 32] = v1;
            }
        }
    }
}

// ---------------------------------------------------------------------------
// Same GEMM but A is fp32 (converted to bf16 during LDS staging). Used for G1.
// ---------------------------------------------------------------------------
__global__ __launch_bounds__(256) void gemm_lds_a32_kernel(
    const float* __restrict__ A, int lda,
    const __hip_bfloat16* __restrict__ Bt, int ldb, int bRowOff,
    const float* __restrict__ bias, int biasOff,
    __hip_bfloat16* __restrict__ Cout, int ldc, int cColOff,
    int M, int K)
{
    __shared__ short As[128 * 64];
    __shared__ short Bs[128 * 64];

    const int tid  = threadIdx.x;
    const int lane = tid & 63;
    const int wave = tid >> 6;
    const int wm   = (wave >> 1) << 6;
    const int wn   = (wave & 1) << 6;
    const int l31  = lane & 31;
    const int ch   = lane >> 5;
    const int e7   = l31 & 7;

    const int m0 = blockIdx.x * 128;
    const int y  = blockIdx.y;
    const short* Bb = (const short*)Bt + (size_t)y * bRowOff * ldb;

    const int rr = tid >> 3;
    const int cc = tid & 7;
    const int sbase = rr * 64 + (((cc ^ (rr & 7)) << 3));
    const float* pA[4];
    const short* pB[4];
#pragma unroll
    for (int i = 0; i < 4; i++) {
        int r = i * 32 + rr;
        int gr = m0 + r; gr = gr < M ? gr : (M - 1);
        pA[i] = A + (size_t)gr * lda + cc * 8;
        pB[i] = Bb + (size_t)r * ldb + cc * 8;
    }

    floatx16 acc[2][2];
#pragma unroll
    for (int a = 0; a < 2; a++)
#pragma unroll
        for (int b = 0; b < 2; b++)
#pragma unroll
            for (int i = 0; i < 16; i++) acc[a][b][i] = 0.f;

    const int ra0 = (wm + l31) * 64;
    const int ra1 = (wm + 32 + l31) * 64;
    const int rb0 = (wn + l31) * 64;
    const int rb1 = (wn + 32 + l31) * 64;

    for (int k0 = 0; k0 < K; k0 += 64) {
#pragma unroll
        for (int i = 0; i < 4; i++) {
            float4 a0 = *(const float4*)(pA[i] + k0);
            float4 a1 = *(const float4*)(pA[i] + k0 + 4);
            int4 bv = *(const int4*)(pB[i] + k0);
            __hip_bfloat16 o[8] = {
                __float2bfloat16(a0.x), __float2bfloat16(a0.y),
                __float2bfloat16(a0.z), __float2bfloat16(a0.w),
                __float2bfloat16(a1.x), __float2bfloat16(a1.y),
                __float2bfloat16(a1.z), __float2bfloat16(a1.w)};
            *(int4*)(As + i * 2048 + sbase) = *(int4*)o;
            *(int4*)(Bs + i * 2048 + sbase) = bv;
        }
        __syncthreads();
#pragma unroll
        for (int ks = 0; ks < 4; ks++) {
            const int sw = (((ks << 1) + ch) ^ e7) << 3;
            short8 a0 = *(const short8*)(As + ra0 + sw);
            short8 a1 = *(const short8*)(As + ra1 + sw);
            short8 b0 = *(const short8*)(Bs + rb0 + sw);
            short8 b1 = *(const short8*)(Bs + rb1 + sw);
            acc[0][0] = __builtin_amdgcn_mfma_f32_32x32x16_bf16(a0, b0, acc[0][0], 0, 0, 0);
            acc[0][1] = __builtin_amdgcn_mfma_f32_32x32x16_bf16(a0, b1, acc[0][1], 0, 0, 0);
            acc[1][0] = __builtin_amdgcn_mfma_f32_32x32x16_bf16(a1, b0, acc[1][0], 0, 0, 0);
            acc[1][1] = __builtin_amdgcn_mfma_f32_32x32x16_bf16(a1, b1, acc[1][1], 0, 0, 0);
        }
        __syncthreads();
    }

    const int colL0 = wn + l31;
    const int ccol  = y * cColOff;
    const float bv0 = bias ? bias[y * biasOff + colL0] : 0.f;
    const float bv1 = bias ? bias[y * biasOff + colL0 + 32] : 0.f;
    const int rb = m0 + wm + ((lane >> 5) << 2);

#pragma unroll
    for (int tm = 0; tm < 2; tm++) {
#pragma unroll
        for (int rg = 0; rg < 16; rg++) {
            int row = rb + tm * 32 + (rg & 3) + ((rg >> 2) << 3);
            if (row >= M) continue;
            float v0 = acc[tm][0][rg] + bv0;
            float v1 = acc[tm][1][rg] + bv1;
            v0 = v0 > 0.f ? v0 : 0.01f * v0;
            v1 = v1 > 0.f ? v1 : 0.01f * v1;
            Cout[(size_t)row * ldc + ccol + colL0]      = __float2bfloat16(v0);
            Cout[(size_t)row * ldc + ccol + colL0 + 32] = __float2bfloat16(v1);
        }
    }
}

// ---------------------------------------------------------------------------
// All weight prep in ONE kernel (W1t, W2t, W3et replicated, b1c, b2c).
// ---------------------------------------------------------------------------
__global__ __launch_bounds__(256) void prep_weights_kernel(
    const float* __restrict__ W1_0, const float* __restrict__ W1_1, const float* __restrict__ W1_2,
    const float* __restrict__ W2_0, const float* __restrict__ W2_1, const float* __restrict__ W2_2,
    const float* __restrict__ W3,
    const float* __restrict__ b1_0, const float* __restrict__ b1_1, const float* __restrict__ b1_2,
    const float* __restrict__ b2_0, const float* __restrict__ b2_1, const float* __restrict__ b2_2,
    __hip_bfloat16* __restrict__ W1t, __hip_bfloat16* __restrict__ W2t,
    __hip_bfloat16* __restrict__ W3et, float* __restrict__ b1c, float* __restrict__ b2c)
{
    int idx = blockIdx.x * 256 + threadIdx.x;
    if (idx < 98304) {                       // W1: 3 * 256*128
        int r = idx >> 15, rem = idx & 32767;
        int k = rem >> 7, n = rem & 127;
        const float* W = (r == 0) ? W1_0 : (r == 1) ? W1_1 : W1_2;
        W1t[(size_t)(r * 128 + n) * 256 + k] = __float2bfloat16(W[rem]);
    } else if (idx < 147456) {               // W2: 3 * 128*128
        int j = idx - 98304;
        int r = j >> 14, rem = j & 16383;
        int k = rem >> 7, n = rem & 127;
        const float* W = (r == 0) ? W2_0 : (r == 1) ? W2_1 : W2_2;
        W2t[(size_t)r * 16384 + n * 128 + k] = __float2bfloat16(W[rem]);
    } else if (idx < 196608) {               // W3eff: 384*128, replicated x3
        int j = idx - 147456;
        int row = j >> 7, c = j & 127;
        int kk = row >> 7, hh = row & 127;
        const float t[3][3] = {{3.f, -3.f, 0.75f},
                               {0.f,  3.f, -1.5f},
                               {0.f,  0.f, 0.75f}};
        float s = 0.f;
        for (int jj = 0; jj < 3; jj++)
            s += t[jj][kk] * W3[((size_t)jj * HDIM + hh) * HDIM + c];
        __hip_bfloat16 sb = __float2bfloat16(s);
        W3et[(size_t)c * TB_LD + row]       = sb;
        W3et[(size_t)c * TB_LD + 384 + row] = sb;
        W3et[(size_t)c * TB_LD + 768 + row] = sb;
    } else if (idx < 196992) {               // b1c
        int j = idx - 196608;
        const float* b = (j < 128) ? b1_0 : (j < 256) ? b1_1 : b1_2;
        b1c[j] = b[j & 127];
    } else if (idx < 197376) {               // b2c
        int j = idx - 196992;
        const float* b = (j < 128) ? b2_0 : (j < 256) ? b2_1 : b2_2;
        b2c[j] = b[j & 127];
    }
}

// ---------------------------------------------------------------------------
// Bucketed CSR build (R7 structure + R8 LDS-scan). Bucket = 256 dst nodes.
// ---------------------------------------------------------------------------
__global__ __launch_bounds__(256) void bin_kernel(
    const int* __restrict__ s0, const int* __restrict__ s1, const int* __restrict__ s2,
    const int* __restrict__ d0, const int* __restrict__ d1, const int* __restrict__ d2,
    int* __restrict__ bcur,      // [3][NBUCK], pre-zeroed
    int* __restrict__ binned,    // [3][NBUCK][BCAP]
    int nE)
{
    __shared__ int hist[NBUCK];
    __shared__ int claim[NBUCK];
    const int t = threadIdx.x;
    const int y = blockIdx.y;
    const int* sp = (y == 0) ? s0 : (y == 1) ? s1 : s2;
    const int* dp = (y == 0) ? d0 : (y == 1) ? d1 : d2;
    const int base = blockIdx.x * 4096;

    hist[t] = 0;
    __syncthreads();

    int pk[16], bk[16], rk[16];
#pragma unroll
    for (int j = 0; j < 16; j++) {
        int e = base + j * 256 + t;
        if (e < nE) {
            int s = sp[e], d = dp[e];
            bk[j] = d >> 8;
            pk[j] = s | ((d & 255) << 16);
            rk[j] = atomicAdd(&hist[bk[j]], 1);
        } else {
            bk[j] = -1;
        }
    }
    __syncthreads();
    int cnt = hist[t];
    claim[t] = (cnt > 0) ? atomicAdd(&bcur[y * NBUCK + t], cnt) : 0;
    __syncthreads();
#pragma unroll
    for (int j = 0; j < 16; j++) {
        if (bk[j] >= 0) {
            int pos = claim[bk[j]] + rk[j];
            if (pos < BCAP)
                binned[((size_t)(y * NBUCK + bk[j])) * BCAP + pos] = pk[j];
        }
    }
}

__global__ __launch_bounds__(256) void scan_bcur_kernel(
    const int* __restrict__ bcur, int* __restrict__ bbase)
{
    __shared__ int sdata[256];
    const int t = threadIdx.x;
    for (int y = 0; y < 3; y++) {
        int v = bcur[y * NBUCK + t];
        sdata[t] = v;
        __syncthreads();
        for (int off = 1; off < 256; off <<= 1) {
            int x = (t >= off) ? sdata[t - off] : 0;
            __syncthreads();
            sdata[t] += x;
            __syncthreads();
        }
        bbase[y * NBUCK + t] = sdata[t] - v;
        __syncthreads();
    }
}

__global__ __launch_bounds__(256) void deg_kernel2(
    const int* __restrict__ bcur, const int* __restrict__ bbase,
    const int* __restrict__ binned,
    int* __restrict__ rowstart, float* __restrict__ dinvAll, int N)
{
    __shared__ int hist[256];
    __shared__ int scanbuf[256];
    const int t = threadIdx.x;
    const int b = blockIdx.x;
    const int y = blockIdx.y;
    hist[t] = 0;
    __syncthreads();
    const int count = bcur[y * NBUCK + b];
    const int* eb = binned + ((size_t)(y * NBUCK + b)) * BCAP;
    for (int i = t; i < count; i += 256)
        atomicAdd(&hist[(eb[i] >> 16) & 255], 1);
    __syncthreads();
    int hv = hist[t];
    scanbuf[t] = hv;
    __syncthreads();
    for (int off = 1; off < 256; off <<= 1) {
        int x = (t >= off) ? scanbuf[t - off] : 0;
        __syncthreads();
        scanbuf[t] += x;
        __syncthreads();
    }
    int excl = scanbuf[t] - hv;
    int node = (b << 8) + t;
    int base = bbase[y * NBUCK + b];
    if (node < N) {
        rowstart[(size_t)y * (N + 1) + node] = base + excl;
        float d = hv > 1 ? (float)hv : 1.0f;
        dinvAll[(size_t)y * N + node] = 1.0f / sqrtf(d);
    } else if (node == N) {
        rowstart[(size_t)y * (N + 1) + node] = base + excl;   // == E
    }
}

__global__ __launch_bounds__(256) void place_kernel2(
    const int* __restrict__ bcur, const int* __restrict__ binned,
    const int* __restrict__ rowstart, unsigned short* __restrict__ ebuf,
    int N, int nE)
{
    __shared__ int cur[256];
    const int t = threadIdx.x;
    const int b = blockIdx.x;
    const int y = blockIdx.y;
    int node = (b << 8) + t;
    cur[t] = rowstart[(size_t)y * (N + 1) + (node < N ? node : N)];
    __syncthreads();
    const int count = bcur[y * NBUCK + b];
    const int* eb = binned + ((size_t)(y * NBUCK + b)) * BCAP;
    unsigned short* ebo = ebuf + (size_t)y * nE;
    for (int i = t; i < count; i += 256) {
        int p = eb[i];
        int pos = atomicAdd(&cur[(p >> 16) & 255], 1);
        ebo[pos] = (unsigned short)(p & 0xFFFF);
    }
}

// ---------------------------------------------------------------------------
// Fused gather-aggregate + fixup (fp32 accumulation), UNSPLIT columns (R7
// shape — R8's 64B column split cost 1.66x HBM fetch from 128B line grain).
// 16 lanes/node x 16 B = 256 B contiguous per source row; 8-edge unroll for
// memory-level parallelism (R7 was latency-bound at 2.9 TB/s, VALU 34%).
// ---------------------------------------------------------------------------
__device__ inline float bflo(unsigned u) {
    return __builtin_bit_cast(float, u << 16);
}
__device__ inline float bfhi(unsigned u) {
    return __builtin_bit_cast(float, u & 0xffff0000u);
}

__device__ inline void acc8(float* s, uint4 u, float w) {
    s[0] += bflo(u.x) * w; s[1] += bfhi(u.x) * w;
    s[2] += bflo(u.y) * w; s[3] += bfhi(u.y) * w;
    s[4] += bflo(u.z) * w; s[5] += bfhi(u.z) * w;
    s[6] += bflo(u.w) * w; s[7] += bfhi(u.w) * w;
}

__global__ __launch_bounds__(256) void gather_agg_kernel(
    const int* __restrict__ rowstart, const unsigned short* __restrict__ ebufAll,
    const float* __restrict__ dinvAll, __hip_bfloat16* __restrict__ T,
    int inBase, int outBase, int N, int nE)
{
    int v = blockIdx.x * 16 + (threadIdx.x >> 4);
    if (v >= N) return;
    const int y = blockIdx.y;
    const int* rs = rowstart + (size_t)y * (N + 1);
    const unsigned short* eb = ebufAll + (size_t)y * nE;
    const float* dinv = dinvAll + (size_t)y * N;
    const int inOff  = y * 384 + inBase  + ((threadIdx.x & 15) << 3);
    const int outOff = y * 384 + outBase + ((threadIdx.x & 15) << 3);

    const unsigned short* Tu = (const unsigned short*)T;
    const int beg = rs[v];
    const int end = rs[v + 1];

    float s[8];
#pragma unroll
    for (int j = 0; j < 8; j++) s[j] = 0.f;

    int i = beg;
    for (; i + 7 < end; i += 8) {
        int n0 = eb[i],     n1 = eb[i + 1], n2 = eb[i + 2], n3 = eb[i + 3];
        int n4 = eb[i + 4], n5 = eb[i + 5], n6 = eb[i + 6], n7 = eb[i + 7];
        float w0 = dinv[n0], w1 = dinv[n1], w2 = dinv[n2], w3 = dinv[n3];
        float w4 = dinv[n4], w5 = dinv[n5], w6 = dinv[n6], w7 = dinv[n7];
        uint4 u0 = *(const uint4*)(Tu + (size_t)n0 * TB_LD + inOff);
        uint4 u1 = *(const uint4*)(Tu + (size_t)n1 * TB_LD + inOff);
        uint4 u2 = *(const uint4*)(Tu + (size_t)n2 * TB_LD + inOff);
        uint4 u3 = *(const uint4*)(Tu + (size_t)n3 * TB_LD + inOff);
        uint4 u4 = *(const uint4*)(Tu + (size_t)n4 * TB_LD + inOff);
        uint4 u5 = *(const uint4*)(Tu + (size_t)n5 * TB_LD + inOff);
        uint4 u6 = *(const uint4*)(Tu + (size_t)n6 * TB_LD + inOff);
        uint4 u7 = *(const uint4*)(Tu + (size_t)n7 * TB_LD + inOff);
        acc8(s, u0, w0); acc8(s, u1, w1); acc8(s, u2, w2); acc8(s, u3, w3);
        acc8(s, u4, w4); acc8(s, u5, w5); acc8(s, u6, w6); acc8(s, u7, w7);
    }
    for (; i + 1 < end; i += 2) {
        int n0 = eb[i], n1 = eb[i + 1];
        float w0 = dinv[n0], w1 = dinv[n1];
        uint4 u0 = *(const uint4*)(Tu + (size_t)n0 * TB_LD + inOff);
        uint4 u1 = *(const uint4*)(Tu + (size_t)n1 * TB_LD + inOff);
        acc8(s, u0, w0); acc8(s, u1, w1);
    }
    if (i < end) {
        int n0 = eb[i];
        float w0 = dinv[n0];
        uint4 u0 = *(const uint4*)(Tu + (size_t)n0 * TB_LD + inOff);
        acc8(s, u0, w0);
    }

    const float di = dinv[v];
    uint4 uv = *(const uint4*)(Tu + (size_t)v * TB_LD + inOff);
    float r[8] = {bflo(uv.x) - s[0] * di, bfhi(uv.x) - s[1] * di,
                  bflo(uv.y) - s[2] * di, bfhi(uv.y) - s[3] * di,
                  bflo(uv.z) - s[4] * di, bfhi(uv.z) - s[5] * di,
                  bflo(uv.w) - s[6] * di, bfhi(uv.w) - s[7] * di};
    __hip_bfloat16 o[8];
#pragma unroll
    for (int j = 0; j < 8; j++) o[j] = __float2bfloat16(r[j]);
    *(uint4*)(T + (size_t)v * TB_LD + outOff) = *(uint4*)o;
}

// ---------------------------------------------------------------------------
extern "C" void kernel_launch(void* const* d_in, const int* in_sizes, int n_in,
                              void* d_out, int out_size, void* d_ws, size_t ws_size,
                              hipStream_t stream)
{
    const int N = in_sizes[0] / 256;
    const int E = in_sizes[1];
    const int IN = 256;

    const float* x = (const float*)d_in[0];
    const int* srcp[3]; const int* dstp[3];
    const float *W1p[3], *b1p[3], *W2p[3], *b2p[3];
    if (in_sizes[3] == E) {
        for (int r = 0; r < 3; r++) {
            srcp[r] = (const int*)d_in[1 + 2 * r];
            dstp[r] = (const int*)d_in[2 + 2 * r];
            W1p[r]  = (const float*)d_in[7 + 4 * r];
            b1p[r]  = (const float*)d_in[8 + 4 * r];
            W2p[r]  = (const float*)d_in[9 + 4 * r];
            b2p[r]  = (const float*)d_in[10 + 4 * r];
        }
    } else {
        for (int r = 0; r < 3; r++) {
            int base = 1 + 6 * r;
            srcp[r] = (const int*)d_in[base];
            dstp[r] = (const int*)d_in[base + 1];
            W1p[r]  = (const float*)d_in[base + 2];
            b1p[r]  = (const float*)d_in[base + 3];
            W2p[r]  = (const float*)d_in[base + 4];
            b2p[r]  = (const float*)d_in[base + 5];
        }
    }
    const float* W3 = (const float*)d_in[19];
    const float* b3 = (const float*)d_in[20];
    float* out = (float*)d_out;

    // Workspace (256B-aligned chunks)
    char* w = (char*)d_ws;
    auto alloc = [&](size_t bytes) { char* p = w; w += (bytes + 255) & ~(size_t)255; return p; };
    __hip_bfloat16* Tball = (__hip_bfloat16*)alloc((size_t)N * TB_LD * 2);
    __hip_bfloat16* Hb    = (__hip_bfloat16*)alloc((size_t)N * 384 * 2);
    __hip_bfloat16* W1t   = (__hip_bfloat16*)alloc((size_t)384 * IN * 2);
    __hip_bfloat16* W2t   = (__hip_bfloat16*)alloc((size_t)3 * HDIM * HDIM * 2);
    __hip_bfloat16* W3et  = (__hip_bfloat16*)alloc((size_t)HDIM * TB_LD * 2);
    float* b1c    = (float*)alloc(384 * 4);
    float* b2c    = (float*)alloc(384 * 4);
    float* dinv   = (float*)alloc((size_t)3 * N * 4);
    int* rowstart = (int*)alloc((size_t)3 * (N + 1) * 4);
    int* bcur     = (int*)alloc((size_t)3 * NBUCK * 4);
    int* bbase    = (int*)alloc((size_t)3 * NBUCK * 4);
    unsigned short* ebuf = (unsigned short*)alloc((size_t)3 * E * 2);
    int* binned   = (int*)alloc((size_t)3 * NBUCK * BCAP * 4);

    const int mGrid = (N + 127) / 128;
    const int nBuck = (N + 255) >> 8;
    const int binGrid = (E + 4095) / 4096;
    const int nodeGrid = (N + 15) / 16;

    // ---- prep ----
    prep_weights_kernel<<<(197376 + 255) / 256, 256, 0, stream>>>(
        W1p[0], W1p[1], W1p[2], W2p[0], W2p[1], W2p[2], W3,
        b1p[0], b1p[1], b1p[2], b2p[0], b2p[1], b2p[2],
        W1t, W2t, W3et, b1c, b2c);

    // ---- bucketed CSR build (all relations) ----
    hipMemsetAsync(bcur, 0, (size_t)3 * NBUCK * sizeof(int), stream);
    bin_kernel<<<dim3(binGrid, 3), 256, 0, stream>>>(
        srcp[0], srcp[1], srcp[2], dstp[0], dstp[1], dstp[2], bcur, binned, E);
    scan_bcur_kernel<<<1, 256, 0, stream>>>(bcur, bbase);
    deg_kernel2<<<dim3(nBuck, 3), 256, 0, stream>>>(bcur, bbase, binned,
                                                    rowstart, dinv, N);
    place_kernel2<<<dim3(nBuck, 3), 256, 0, stream>>>(bcur, binned, rowstart,
                                                      ebuf, N, E);

    // ---- G1: Hb[N,384] = leaky(x(fp32) @ [W1_0|W1_1|W1_2] + b1c) ----
    gemm_lds_a32_kernel<<<dim3(mGrid, 3), 256, 0, stream>>>(
        x, IN, W1t, IN, 128, b1c, 128, Hb, 384, 128, N, IN);

    // ---- G2: Tball[:, y*384:+128] = leaky(Hb[:, y*128:+128] @ W2_y + b2_y)
    gemm_lds_kernel<<<dim3(mGrid, 3), 256, 0, stream>>>(
        Hb, 384, 128, W2t, HDIM, 128, b2c, 128, Tball, TB_LD, 384, N, HDIM,
        GF_LEAKY | GF_BF16);

    // ---- poly features: hop1 (h -> f1), hop2 (f1 -> f2) ----
    gather_agg_kernel<<<dim3(nodeGrid, 3), 256, 0, stream>>>(
        rowstart, ebuf, dinv, Tball, 0, 128, N, E);
    gather_agg_kernel<<<dim3(nodeGrid, 3), 256, 0, stream>>>(
        rowstart, ebuf, dinv, Tball, 128, 256, N, E);

    // ---- final: out = leaky(Tball @ W3et_cat + b3), K=1152, one shot ----
    gemm_lds_kernel<<<dim3(mGrid, 1), 256, 0, stream>>>(
        Tball, TB_LD, 0, W3et, TB_LD, 0, b3, 0, out, HDIM, 0, N, TB_LD,
        GF_LEAKY);
}